// Round 14
// baseline (9734.869 us; speedup 1.0000x reference)
//
#include <hip/hip_runtime.h>
#include <stdint.h>

#define NU 4096
#define NB 2048
#define KK2 8192            // i8 bytes per Bt column: 2 levels x 4096
#define ITERS 100
#define CAP 262144
#define THETA 0.05f
#define KC 512              // host fixup k-panel (verified)
#define S1 0.03937007874f   // 5/127 — level-1 quant step
#define S2 (S1 / 254.0f)    // level-2 step; range = S1/2 exactly

// ws layout (bytes) — unchanged
#define OFF_BT   0u
#define OFF_A0   67108864u
#define OFF_A1   83886080u
#define OFF_SUS  100663296u
#define OFF_CNT  102760448u
#define REQ_WS   102761472u

// ROUND-14 — A out of LDS: fragment-major tiled A + direct global->reg loads.
// A layout (we own it; init/epilogue/fixup/emit all updated): chunk (kt,r16)
// = 1024 B at byte ((kt*128 + r16)*64 + lane)*16, lane = lm + 16*lk, holding
// A[r16*16+lm][kt*64 + lk*16 + b]. One wave ald = 1 KB contiguous (perfectly
// coalesced), MFMA-ready. A-slice/tile = 16 KB shared by 32 blocks -> L2-hot.
// A primed 2 tiles ahead via inline-asm global_load_dwordx4 (compiler can't
// track asm loads -> my VMW ledger is the wait; SCB fences per rule 18).
// B: gl16-staged as R13 but slab = 16 KB (B1 @0, B2 @8192), 8 slabs =
// 128 KB, staged SIX tiles ahead (deeper than R13's 4 — R13 proved distance
// is the lever). bh primed 1 tile ahead (ds_read); bl read in-tile (R10 vs
// R12: free).
// vmcnt FIFO ledger (per wave/tile, order SCB-pinned: [A(k+2):4, B(k+6):2]):
// end of tile k needs A(k+1) (issued first in tile k-1) -> ops after it =
// B(k+5):2 + A(k+2):4 + B(k+6):2 = VMW(8). Retires A(k+1) (~1.7 tiles old)
// and B(k+5) (2+ tiles). Tail (A guard k+2<NT, B guard k+6<NT): k=58 ->
// VMW(6); k=59..61 -> VMW(4); k>=62 -> VMW(0) (enumerated). Slab WAR: slab
// m read (primes) during m-1, restaged during m+2 — >=2 barriers apart.
// Registers: A 3 sets x16 + bh 2x16 + bl 1x16 = 96 frag VGPR (== R13's 96).
// SLOT SWIZZLE for B (measured 0 conflicts R6..R13): congruences unchanged.
#define NT 64

typedef int i32x4 __attribute__((ext_vector_type(4)));

__device__ __forceinline__ void gl16(const void* g, void* l) {
  __builtin_amdgcn_global_load_lds(
      (const __attribute__((address_space(1))) unsigned int*)g,
      (__attribute__((address_space(3))) unsigned int*)l, 16, 0, 0);
}

__device__ __forceinline__ i32x4 ald(const signed char* p) {
  i32x4 r;
  asm volatile("global_load_dwordx4 %0, %1, off" : "=v"(r) : "v"(p));
  return r;
}

__global__ void fill_kernel(float* __restrict__ out, float v) {
  int t = blockIdx.x * blockDim.x + threadIdx.x;
  int base = t << 3;
  float4 a = make_float4(v, v, v, v);
  *(float4*)(out + base) = a;
  *(float4*)(out + base + 4) = a;
}

__device__ __forceinline__ int q127(float x, float s) {
  int v = (int)rintf(x / s);
  return v < -127 ? -127 : (v > 127 ? 127 : v);
}

// W f32 -> two i8 planes: Bt[col*8192 + k] = I1, Bt[col*8192 + 4096 + k] = I2.
__global__ void decompose_kernel(const float* __restrict__ W,
                                 signed char* __restrict__ Bt) {
  int t = blockIdx.x * blockDim.x + threadIdx.x;
  int base = t << 2;
  int j = base >> 12;
  int k = base & 4095;
  float4 w = *(const float4*)(W + (size_t)j * NU + k);
  int a0 = q127(w.x, S1), a1 = q127(w.y, S1), a2 = q127(w.z, S1), a3 = q127(w.w, S1);
  float r0 = w.x - (float)a0 * S1, r1 = w.y - (float)a1 * S1;
  float r2 = w.z - (float)a2 * S1, r3 = w.w - (float)a3 * S1;
  int b0 = q127(r0, S2), b1 = q127(r1, S2), b2 = q127(r2, S2), b3 = q127(r3, S2);
  uchar4 p1 = make_uchar4((unsigned char)a0, (unsigned char)a1,
                          (unsigned char)a2, (unsigned char)a3);
  uchar4 p2 = make_uchar4((unsigned char)b0, (unsigned char)b1,
                          (unsigned char)b2, (unsigned char)b3);
  *(uchar4*)(Bt + (size_t)j * KK2 + k) = p1;
  *(uchar4*)(Bt + (size_t)j * KK2 + 4096 + k) = p2;
}

// P (fp32 +-1) -> A0 in fragment-major tiled layout. Thread = (row, kc16):
// reads 16 f32, writes 16 i8 at ((kc>>2)*128 + row>>4)*1024 + (row&15)*16
// + (kc&3)*256.
__global__ void init_kernel(const float* __restrict__ P,
                            signed char* __restrict__ A0) {
  int t = blockIdx.x * blockDim.x + threadIdx.x;   // 524288 threads
  int row = t >> 8, kc = t & 255;
  const float4* p = (const float4*)(P + (size_t)row * NU + (kc << 4));
  float4 v0 = p[0], v1 = p[1], v2 = p[2], v3 = p[3];
  float hv[16] = {v0.x, v0.y, v0.z, v0.w, v1.x, v1.y, v1.z, v1.w,
                  v2.x, v2.y, v2.z, v2.w, v3.x, v3.y, v3.z, v3.w};
  unsigned un[4];
#pragma unroll
  for (int g = 0; g < 4; ++g) {
    unsigned u = 0;
#pragma unroll
    for (int i = 0; i < 4; ++i) {
      unsigned char s = (hv[g * 4 + i] >= 0.0f) ? 0x01u : 0xFFu;
      u |= ((unsigned)s) << (i * 8);
    }
    un[g] = u;
  }
  uint4 pk = make_uint4(un[0], un[1], un[2], un[3]);
  size_t addr = ((size_t)(kc >> 2) << 17) + ((size_t)(row >> 4) << 10) +
                ((row & 15) << 4) + ((kc & 3) << 8);
  *(uint4*)(A0 + addr) = pk;
}

// Final output: tiled A (i8 signs) -> row-major f32 +-1.
__global__ void emit_kernel(const signed char* __restrict__ A,
                            float* __restrict__ out) {
  int t = blockIdx.x * blockDim.x + threadIdx.x;   // 1048576 threads
  int row = t >> 9, k8 = (t & 511) << 3;
  size_t addr = ((size_t)(k8 >> 6) << 17) + ((size_t)(row >> 4) << 10) +
                ((row & 15) << 4) + (((k8 >> 4) & 3) << 8) + (k8 & 15);
  uint2 pk = *(const uint2*)(A + addr);
  float4 o0, o1;
  o0.x = (pk.x & 0x80u) ? -1.0f : 1.0f;
  o0.y = (pk.x & 0x8000u) ? -1.0f : 1.0f;
  o0.z = (pk.x & 0x800000u) ? -1.0f : 1.0f;
  o0.w = (pk.x & 0x80000000u) ? -1.0f : 1.0f;
  o1.x = (pk.y & 0x80u) ? -1.0f : 1.0f;
  o1.y = (pk.y & 0x8000u) ? -1.0f : 1.0f;
  o1.z = (pk.y & 0x800000u) ? -1.0f : 1.0f;
  o1.w = (pk.y & 0x80000000u) ? -1.0f : 1.0f;
  *(float4*)(out + (size_t)row * NU + k8) = o0;
  *(float4*)(out + (size_t)row * NU + k8 + 4) = o1;
}

// ---- schedule primitives ----
#define SCB() __builtin_amdgcn_sched_barrier(0)
#define BAR() do { __builtin_amdgcn_sched_barrier(0);          \
                   __builtin_amdgcn_s_barrier();               \
                   __builtin_amdgcn_sched_barrier(0); } while (0)
#define VMW(N) do { asm volatile("s_waitcnt vmcnt(" #N ")" ::: "memory"); \
                    __builtin_amdgcn_sched_barrier(0); } while (0)
#define MMX(AF, BF, ACC)                                                      \
  _Pragma("unroll") for (int i_ = 0; i_ < 4; ++i_)                            \
  _Pragma("unroll") for (int j_ = 0; j_ < 4; ++j_)                            \
    ACC[i_][j_] = __builtin_amdgcn_mfma_i32_16x16x64_i8(                      \
        AF[i_], BF[j_], ACC[i_][j_], 0, 0, 0);
#define RD4S(DST, BASE) _Pragma("unroll")                                     \
  for (int q_ = 0; q_ < 4; ++q_)                                              \
    DST[q_] = *(const i32x4*)((BASE) + q_ * 1024);

// A-prime: 4 asm loads, 1 KB apart (q = r16 sub-index).
#define APRIME(PA, kt)                                                        \
  {                                                                           \
    const signed char* pa_ = pA0 + ((size_t)(kt) << 17);                      \
    PA[0] = ald(pa_);          PA[1] = ald(pa_ + 1024);                       \
    PA[2] = ald(pa_ + 2048);   PA[3] = ald(pa_ + 3072);                       \
  }

// Full-rate tile body (no guards; valid for k <= 53): compute tile k with
// A set CA / bh set CH; prime A(k+2)->PA, bh(k+1)->PH; bl(k) read in-tile;
// stage B(k+6). Order within tile SCB-pinned: [bl ds | A-asm | gl16+bh ds].
#define TBF(k, CA, PA, CH, PH)                                                \
  {                                                                           \
    SCB();                                                                    \
    MMX(CA, CH, acc1);                                                        \
    SCB();                                                                    \
    RD4S(bl, sL + (((k) & 7) << 14) + 8192 + bOff);                           \
    SCB();                                                                    \
    APRIME(PA, (k) + 2);                                                      \
    SCB();                                                                    \
    {                                                                         \
      const int kS_ = ((k) + 6) << 6;                                         \
      unsigned char* sS_ = sL + ((((k) + 6) & 7) << 14);                      \
      gl16(pBsH + kS_, sS_ + ldsB);                                           \
      gl16(pBsL + kS_, sS_ + 8192 + ldsB);                                    \
    }                                                                         \
    RD4S(PH, sL + ((((k) + 1) & 7) << 14) + bOff);                            \
    SCB();                                                                    \
    MMX(CA, bl, acc2);                                                        \
    SCB();                                                                    \
    VMW(8);                                                                   \
    BAR();                                                                    \
  }

// Tail tile body (literal k, guarded; VMW per enumerated ledger).
#define TBT(k, CA, PA, CH, PH)                                                \
  {                                                                           \
    SCB();                                                                    \
    MMX(CA, CH, acc1);                                                        \
    SCB();                                                                    \
    RD4S(bl, sL + (((k) & 7) << 14) + 8192 + bOff);                           \
    SCB();                                                                    \
    if ((k) + 2 < NT) { APRIME(PA, (k) + 2); }                                \
    SCB();                                                                    \
    if ((k) + 6 < NT) {                                                       \
      const int kS_ = ((k) + 6) << 6;                                         \
      unsigned char* sS_ = sL + ((((k) + 6) & 7) << 14);                      \
      gl16(pBsH + kS_, sS_ + ldsB);                                           \
      gl16(pBsL + kS_, sS_ + 8192 + ldsB);                                    \
    }                                                                         \
    if ((k) + 1 < NT) {                                                       \
      RD4S(PH, sL + ((((k) + 1) & 7) << 14) + bOff);                          \
    }                                                                         \
    SCB();                                                                    \
    MMX(CA, bl, acc2);                                                        \
    SCB();                                                                    \
    if ((k) <= NT - 7) { VMW(8); }                                            \
    else if ((k) == NT - 6) { VMW(6); }                                       \
    else if ((k) <= NT - 3) { VMW(4); }                                       \
    else { VMW(0); }                                                          \
    BAR();                                                                    \
  }

__global__ void __launch_bounds__(512, 1)
gemm_fused_kernel(const signed char* __restrict__ A,
                  const signed char* __restrict__ Bt,
                  signed char* __restrict__ Anext,
                  int* __restrict__ counter,
                  int* __restrict__ suspects) {
  __shared__ __align__(16) unsigned char sL[131072];   // 8 x 16 KB B slabs
  const int tid = threadIdx.x;
  const int wave = tid >> 6, lane = tid & 63;
  const int lm = lane & 15, lk = lane >> 4;
  const int wm = wave >> 1, wn = wave & 1;             // 4M x 2N wave grid
  const int nt = blockIdx.x & 31, mt = blockIdx.x >> 5;
  const int mBase = mt << 8, nBase = nt << 7;

  // ---- A fragment base (tiled layout): r16 = mt*16 + wm*4 + q ----
  const signed char* pA0 =
      A + (((size_t)(mt * 16 + wm * 4)) << 10) + (lane << 4);

  // ---- B staging lane constants (R13 verbatim; measured 0 conflicts) ----
  const int rl = lane >> 2;                            // 0..15 rows
  const int cs = ((((lane & 3) - ((lane >> 3) & 3)) & 3) << 4);  // i8 elems
  const signed char* pBsH = Bt + (size_t)(nBase + (wave << 4) + rl) * KK2 + cs;
  const signed char* pBsL = pBsH + 4096;               // level-2 plane
  const int ldsB = wave << 10;                         // wave*1024 (1 gl16)

  // ---- B fragment-read lane constants (R13 verbatim) ----
  const int pslot = (lk + ((lm >> 1) & 3)) & 3;
  const int bOff = (((wn << 6) + lm) << 6) + (pslot << 4);

  i32x4 acc1[4][4] = {};                               // level-1 acc
  i32x4 acc2[4][4] = {};                               // level-2 acc
  i32x4 a0[4], a1[4], a2[4], h0[4], h1[4], bl[4];

  // prologue: stage B tiles 0..5 -> slabs 0..5; load A(0),A(1); publish;
  // prime bh(0).
#pragma unroll
  for (int j = 0; j < 6; ++j) {
    gl16(pBsH + (j << 6), sL + (j << 14) + ldsB);
    gl16(pBsL + (j << 6), sL + (j << 14) + 8192 + ldsB);
  }
  APRIME(a0, 0);
  APRIME(a1, 1);
  VMW(0);
  BAR();
  RD4S(h0, sL + bOff);

  for (int k = 0; k < 54; k += 6) {
    TBF(k + 0, a0, a2, h0, h1);
    TBF(k + 1, a1, a0, h1, h0);
    TBF(k + 2, a2, a1, h0, h1);
    TBF(k + 3, a0, a2, h1, h0);
    TBF(k + 4, a1, a0, h0, h1);
    TBF(k + 5, a2, a1, h1, h0);
  }
  TBT(54, a0, a2, h0, h1);
  TBT(55, a1, a0, h1, h0);
  TBT(56, a2, a1, h0, h1);
  TBT(57, a0, a2, h1, h0);
  TBT(58, a1, a0, h0, h1);
  TBT(59, a2, a1, h1, h0);
  TBT(60, a0, a2, h0, h1);
  TBT(61, a1, a0, h1, h0);
  TBT(62, a2, a1, h0, h1);
  TBT(63, a0, a2, h1, h0);

  // Fused sign epilogue. C/D layout (m89/m91, dtype-independent m121-128):
  // col=lane&15, row=(lane>>4)*4+reg. h = S1*d1 + S2*d2. Anext is TILED.
#pragma unroll
  for (int i = 0; i < 4; ++i)
#pragma unroll
    for (int j = 0; j < 4; ++j)
#pragma unroll
      for (int r = 0; r < 4; ++r) {
        const int row = mBase + (wm << 6) + i * 16 + (lk << 2) + r;
        const int col = nBase + (wn << 6) + j * 16 + lm;
        const float h = S1 * (float)acc1[i][j][r] + S2 * (float)acc2[i][j][r];
        const size_t taddr = ((size_t)(col >> 6) << 17) +
                             ((size_t)(row >> 4) << 10) + ((row & 15) << 4) +
                             (((col >> 4) & 3) << 8) + (col & 15);
        Anext[taddr] = (h >= 0.0f) ? (signed char)1 : (signed char)-1;
        if (fabsf(h) < THETA) {
          int sidx = atomicAdd(counter, 1);
          if (sidx < CAP) suspects[sidx] = (row << 12) | col;
        }
      }
}

// Suspects, 8 lanes per suspect. Exact f32 recompute vs ORIGINAL W.
// A buffers are tiled: addr(b,k) = (k>>6)<<17 | (b>>4)<<10 | (b&15)<<4 |
// ((k>>4)&3)<<8 | (k&15); k%4==0 -> 4 consecutive bytes in one chunk.
__global__ void fixup_kernel(const signed char* __restrict__ Acur,
                             const float* __restrict__ W,
                             signed char* __restrict__ Anext,
                             const int* __restrict__ counter,
                             const int* __restrict__ suspects,
                             int* __restrict__ flagOv) {
  int n = *counter;
  if (blockIdx.x == 0 && threadIdx.x == 0 && n > CAP) atomicAdd(flagOv, 1);
  n = n < CAP ? n : CAP;
  const int lane = threadIdx.x & 7;                       // panel index
  const int gid = (blockIdx.x * blockDim.x + threadIdx.x) >> 3;
  const int ngrp = (gridDim.x * blockDim.x) >> 3;
  for (int i = gid; i < n; i += ngrp) {
    int idx = suspects[i];
    int b = idx >> 12, j = idx & 4095;
    const float* wrow = W + (size_t)j * NU;
    const size_t baseb = ((size_t)(b >> 4) << 10) + ((b & 15) << 4);
    float part = 0.0f;
    const int k0 = lane * KC;
    for (int k = k0; k < k0 + KC; k += 4) {
      float4 wv = *(const float4*)(wrow + k);
      unsigned av = *(const unsigned*)(Acur + (((size_t)(k >> 6)) << 17) +
                                       baseb + (((k >> 4) & 3) << 8) +
                                       (k & 15));
      part += (av & 0x80u) ? -wv.x : wv.x;
      part += (av & 0x8000u) ? -wv.y : wv.y;
      part += (av & 0x800000u) ? -wv.z : wv.z;
      part += (av & 0x80000000u) ? -wv.w : wv.w;
    }
    float c = __shfl(part, 0, 8);
#pragma unroll
    for (int q = 1; q < 8; ++q) c += __shfl(part, q, 8);
    if (lane == 0) {
      const size_t taddr = ((size_t)(j >> 6) << 17) +
                           ((size_t)(b >> 4) << 10) + ((b & 15) << 4) +
                           (((j >> 4) & 3) << 8) + (j & 15);
      Anext[taddr] = (c >= 0.0f) ? (signed char)1 : (signed char)-1;
    }
  }
}

// Tripwire: if the suspect list ever overflows, poison the output signature.
__global__ void assemble_kernel(float* __restrict__ out,
                                const int* __restrict__ flags) {
  if (threadIdx.x != 0 || blockIdx.x != 0) return;
  if (flags[1]) out[0] = 7777.0f;
}

extern "C" void kernel_launch(void* const* d_in, const int* in_sizes, int n_in,
                              void* d_out, int out_size, void* d_ws, size_t ws_size,
                              hipStream_t stream) {
  const float* P = (const float*)d_in[0];
  const float* W = (const float*)d_in[1];
  float* out = (float*)d_out;

  if (n_in < 2 || in_sizes[0] != NB * NU || in_sizes[1] != NU * NU ||
      out_size != NB * NU) {
    fill_kernel<<<4096, 256, 0, stream>>>(out, 9.0f);
    return;
  }
  if (ws_size < (size_t)REQ_WS) {
    fill_kernel<<<4096, 256, 0, stream>>>(out, 3.0f);
    return;
  }

  char* w = (char*)d_ws;
  signed char* Bt = (signed char*)(w + OFF_BT);
  signed char* A0 = (signed char*)(w + OFF_A0);
  signed char* A1 = (signed char*)(w + OFF_A1);
  int* suspects = (int*)(w + OFF_SUS);
  int* counters = (int*)(w + OFF_CNT);
  int* flags = counters + 128;  // [1]=suspect overflow

  hipMemsetAsync(counters, 0, 1024, stream);
  decompose_kernel<<<16384, 256, 0, stream>>>(W, Bt);
  init_kernel<<<2048, 256, 0, stream>>>(P, A0);

  for (int t = 0; t < ITERS; ++t) {
    signed char* Ain = (t & 1) ? A1 : A0;
    signed char* Aout = (t & 1) ? A0 : A1;
    gemm_fused_kernel<<<256, 512, 0, stream>>>(Ain, Bt, Aout,
                                               &counters[t], suspects);
    fixup_kernel<<<256, 256, 0, stream>>>(Ain, W, Aout,
                                          &counters[t], suspects, &flags[1]);
  }
  // A_100 lives in A0 (output buffer of odd t=99).
  emit_kernel<<<4096, 256, 0, stream>>>(A0, out);
  assemble_kernel<<<1, 64, 0, stream>>>(out, flags);
}